// Round 1
// baseline (591.697 us; speedup 1.0000x reference)
//
#include <hip/hip_runtime.h>

#define DEV __device__ __forceinline__

typedef float  f32x4  __attribute__((ext_vector_type(4)));
typedef __bf16 bf16x8 __attribute__((ext_vector_type(8)));

DEV unsigned short f2bf(float f) {
  unsigned u = __float_as_uint(f);
  u += 0x7fffu + ((u >> 16) & 1u);           // round-to-nearest-even
  return (unsigned short)(u >> 16);
}
DEV float bf2f(unsigned v) { return __uint_as_float(v << 16); }

// dims
#define BW   2048
#define NTOK 49
#define CDIM 256
#define HEADS 8
#define HD   32
#define MROWS (BW * NTOK)      // 100352

// ---------------- prep: weights fp32->bf16 + qkv bias assembly --------------
__global__ __launch_bounds__(256) void prep_kernel(
    const float* __restrict__ qkv_w, const float* __restrict__ proj_w,
    const float* __restrict__ q_bias, const float* __restrict__ v_bias,
    unsigned short* __restrict__ wq, unsigned short* __restrict__ wp,
    float* __restrict__ qkvb)
{
  int gid = blockIdx.x * 256 + threadIdx.x;     // grid = 1024 blocks -> 262144
  if (gid < 196608) wq[gid] = f2bf(qkv_w[gid]);
  else              wp[gid - 196608] = f2bf(proj_w[gid - 196608]);
  if (gid < 768)
    qkvb[gid] = (gid < 256) ? q_bias[gid] : ((gid < 512) ? 0.f : v_bias[gid - 512]);
}

// ---------------- CPB MLP: table16[r][h] = 16*sigmoid(mlp(tab[r])) ----------
__global__ __launch_bounds__(64) void cpb_mlp(
    const float* __restrict__ tab, const float* __restrict__ w1,
    const float* __restrict__ b1, const float* __restrict__ w2,
    float* __restrict__ table16)
{
  int r = blockIdx.x;            // 169 rows
  int t = threadIdx.x;           // 64 lanes
  float x0 = tab[r * 2 + 0], x1 = tab[r * 2 + 1];
  float part[8];
#pragma unroll
  for (int h = 0; h < 8; ++h) part[h] = 0.f;
  for (int j = t; j < 512; j += 64) {
    float hv = fmaxf(w1[j * 2 + 0] * x0 + w1[j * 2 + 1] * x1 + b1[j], 0.f);
#pragma unroll
    for (int h = 0; h < 8; ++h) part[h] += hv * w2[h * 512 + j];
  }
#pragma unroll
  for (int h = 0; h < 8; ++h) {
    float v = part[h];
    for (int off = 32; off > 0; off >>= 1) v += __shfl_down(v, off, 64);
    if (t == 0) table16[r * 8 + h] = 16.f / (1.f + expf(-v));
  }
}

// -------- bmT[(h*64+w)*2401 + j*49 + i] = bias16[h][i][j] + mask[w][i][j] ---
__global__ __launch_bounds__(256) void bm_build(
    const float* __restrict__ table16, const int* __restrict__ ridx,
    const float* __restrict__ mask, float* __restrict__ bmT)
{
  int gid = blockIdx.x * 256 + threadIdx.x;
  if (gid >= 512 * 2401) return;
  int h   = gid / (64 * 2401);
  int rem = gid - h * (64 * 2401);
  int w   = rem / 2401;
  int p   = rem - w * 2401;
  int j   = p / 49;
  int i   = p - j * 49;
  bmT[gid] = table16[ridx[i * 49 + j] * 8 + h] + mask[(size_t)w * 2401 + i * 49 + j];
}

// ---------------- bf16 MFMA GEMM: Y[M,N] = A[M,K] @ W[N,K]^T + bias ---------
// 64x64 tile, BK=32, 256 thr = 4 waves, wave -> 16 rows x 64 cols.
template <bool ABF16, bool OBF16>
__global__ __launch_bounds__(256) void gemm_bt(
    const void* __restrict__ Ap, const unsigned short* __restrict__ W,
    const float* __restrict__ bias, void* __restrict__ Yp, int N, int K)
{
  __shared__ short sA[64 * 40];
  __shared__ short sB[64 * 40];
  const int t    = threadIdx.x;
  const int bm   = blockIdx.y * 64;
  const int bn   = blockIdx.x * 64;
  const int r    = t >> 2;
  const int c0   = (t & 3) * 8;
  const int wid  = t >> 6;
  const int l    = t & 63;
  const int quad = l >> 4;
  const int l15  = l & 15;

  f32x4 acc[4];
#pragma unroll
  for (int i = 0; i < 4; ++i) acc[i] = (f32x4){0.f, 0.f, 0.f, 0.f};

  const int KT = K >> 5;
  for (int kt = 0; kt < KT; ++kt) {
    const int k0 = kt << 5;
    if (kt) __syncthreads();
    // stage A (fp32->bf16 convert, or raw bf16 copy)
    if constexpr (ABF16) {
      const unsigned short* ap = (const unsigned short*)Ap + (size_t)(bm + r) * K + k0 + c0;
      *(uint4*)&sA[r * 40 + c0] = *(const uint4*)ap;
    } else {
      const float* ap = (const float*)Ap + (size_t)(bm + r) * K + k0 + c0;
      float4 f0 = *(const float4*)ap;
      float4 f1 = *(const float4*)(ap + 4);
      uint4  u;
      u.x = f2bf(f0.x) | ((unsigned)f2bf(f0.y) << 16);
      u.y = f2bf(f0.z) | ((unsigned)f2bf(f0.w) << 16);
      u.z = f2bf(f1.x) | ((unsigned)f2bf(f1.y) << 16);
      u.w = f2bf(f1.z) | ((unsigned)f2bf(f1.w) << 16);
      *(uint4*)&sA[r * 40 + c0] = u;
    }
    // stage B (W already bf16, [N,K] row-major = BT layout, K-contiguous)
    {
      const unsigned short* wp = W + (size_t)(bn + r) * K + k0 + c0;
      *(uint4*)&sB[r * 40 + c0] = *(const uint4*)wp;
    }
    __syncthreads();
    // compute: 1 A-frag + 4 B-frags -> 4 mfma
    bf16x8 a = *reinterpret_cast<const bf16x8*>(&sA[(wid * 16 + l15) * 40 + quad * 8]);
#pragma unroll
    for (int nt = 0; nt < 4; ++nt) {
      bf16x8 b = *reinterpret_cast<const bf16x8*>(&sB[(nt * 16 + l15) * 40 + quad * 8]);
      acc[nt] = __builtin_amdgcn_mfma_f32_16x16x32_bf16(a, b, acc[nt], 0, 0, 0);
    }
  }
  // epilogue: D row=(quad*4+rr), col=l15 within 16x16 tile
#pragma unroll
  for (int nt = 0; nt < 4; ++nt) {
    const int   col = bn + nt * 16 + l15;
    const float bv  = bias[col];
#pragma unroll
    for (int rr = 0; rr < 4; ++rr) {
      const int row = bm + wid * 16 + quad * 4 + rr;
      float val = acc[nt][rr] + bv;
      if constexpr (OBF16) ((unsigned short*)Yp)[(size_t)row * N + col] = f2bf(val);
      else                 ((float*)Yp)[(size_t)row * N + col] = val;
    }
  }
}

// ---------------- fused window attention: 1 wave per (b,h) ------------------
DEV void load_bf16x32(const unsigned short* p, float* f) {
#pragma unroll
  for (int c = 0; c < 32; c += 8) {
    uint4 u = *(const uint4*)(p + c);
    f[c + 0] = bf2f(u.x & 0xffffu); f[c + 1] = bf2f(u.x >> 16);
    f[c + 2] = bf2f(u.y & 0xffffu); f[c + 3] = bf2f(u.y >> 16);
    f[c + 4] = bf2f(u.z & 0xffffu); f[c + 5] = bf2f(u.z >> 16);
    f[c + 6] = bf2f(u.w & 0xffffu); f[c + 7] = bf2f(u.w >> 16);
  }
}

__global__ __launch_bounds__(64) void attn_win(
    const unsigned short* __restrict__ qkv, const float* __restrict__ logit_scale,
    const float* __restrict__ bmT, unsigned short* __restrict__ aout)
{
  const int h = blockIdx.x;   // 8
  const int b = blockIdx.y;   // 2048
  const int t = threadIdx.x;  // 64 lanes, lane t = query row (t<49)
  __shared__ float kn[49][36];
  __shared__ float vv[49][36];
  const float scale = expf(fminf(logit_scale[h], 4.6051702f));  // exp(min(ls, ln 100))

  float qs[32];
  if (t < 49) {
    const unsigned short* qp = qkv + (size_t)(b * NTOK + t) * 768 + h * HD;
    float q[32], kk[32], vw[32];
    load_bf16x32(qp, q);
    load_bf16x32(qp + 256, kk);
    load_bf16x32(qp + 512, vw);
    float sq = 0.f, sk = 0.f;
#pragma unroll
    for (int d = 0; d < 32; ++d) { sq += q[d] * q[d]; sk += kk[d] * kk[d]; }
    float rq = scale / fmaxf(sqrtf(sq), 1e-12f);
    float rk = 1.f / fmaxf(sqrtf(sk), 1e-12f);
#pragma unroll
    for (int d = 0; d < 32; ++d) {
      qs[d] = q[d] * rq;
      kn[t][d] = kk[d] * rk;
      vv[t][d] = vw[d];
    }
  }
  __syncthreads();
  if (t >= 49) return;

  const float* bm = bmT + ((size_t)h * 64 + (b & 63)) * 2401;

  float att[49];
  float mx = -1e30f;
#pragma unroll
  for (int j = 0; j < 49; ++j) {
    float d0 = 0.f, d1 = 0.f, d2 = 0.f, d3 = 0.f;
#pragma unroll
    for (int d = 0; d < 32; d += 4) {
      d0 += qs[d + 0] * kn[j][d + 0];
      d1 += qs[d + 1] * kn[j][d + 1];
      d2 += qs[d + 2] * kn[j][d + 2];
      d3 += qs[d + 3] * kn[j][d + 3];
    }
    float s = (d0 + d1) + (d2 + d3) + bm[j * 49 + t];  // coalesced across lanes
    att[j] = s;
    mx = fmaxf(mx, s);
  }

  float o[32];
#pragma unroll
  for (int d = 0; d < 32; ++d) o[d] = 0.f;
  float sum = 0.f;
#pragma unroll
  for (int j = 0; j < 49; ++j) {
    float p = __expf(att[j] - mx);
    sum += p;
#pragma unroll
    for (int d = 0; d < 32; ++d) o[d] += p * vv[j][d];
  }
  float rs = 1.f / sum;

  unsigned short* op = aout + (size_t)(b * NTOK + t) * CDIM + h * HD;
#pragma unroll
  for (int c = 0; c < 32; c += 8) {
    uint4 u;
    u.x = f2bf(o[c + 0] * rs) | ((unsigned)f2bf(o[c + 1] * rs) << 16);
    u.y = f2bf(o[c + 2] * rs) | ((unsigned)f2bf(o[c + 3] * rs) << 16);
    u.z = f2bf(o[c + 4] * rs) | ((unsigned)f2bf(o[c + 5] * rs) << 16);
    u.w = f2bf(o[c + 6] * rs) | ((unsigned)f2bf(o[c + 7] * rs) << 16);
    *(uint4*)(op + c) = u;
  }
}

// ---------------------------------------------------------------------------
extern "C" void kernel_launch(void* const* d_in, const int* in_sizes, int n_in,
                              void* d_out, int out_size, void* d_ws, size_t ws_size,
                              hipStream_t stream) {
  const float* x           = (const float*)d_in[0];
  const float* mask        = (const float*)d_in[1];
  const float* qkv_w       = (const float*)d_in[2];
  const float* q_bias      = (const float*)d_in[3];
  const float* v_bias      = (const float*)d_in[4];
  const float* logit_scale = (const float*)d_in[5];
  const float* cpb_w1      = (const float*)d_in[6];
  const float* cpb_b1      = (const float*)d_in[7];
  const float* cpb_w2      = (const float*)d_in[8];
  const float* proj_w      = (const float*)d_in[9];
  const float* proj_b      = (const float*)d_in[10];
  const float* rel_tab     = (const float*)d_in[11];
  const int*   rel_idx     = (const int*)d_in[12];
  float*       out         = (float*)d_out;

  char* ws = (char*)d_ws;
  unsigned short* qkvws   = (unsigned short*)(ws + 0);          // 100352*768*2 = 154140672
  unsigned short* aows    = (unsigned short*)(ws + 154140672);  // 100352*256*2 = 51380224
  unsigned short* wq      = (unsigned short*)(ws + 205520896);  // 393216
  unsigned short* wp      = (unsigned short*)(ws + 205914112);  // 131072
  float*          qkvb    = (float*)(ws + 206045184);           // 3072
  float*          table16 = (float*)(ws + 206048256);           // 5632 (padded)
  float*          bmT     = (float*)(ws + 206053888);           // 512*2401*4 = 4917248
  // total ~211 MB

  prep_kernel<<<1024, 256, 0, stream>>>(qkv_w, proj_w, q_bias, v_bias, wq, wp, qkvb);
  cpb_mlp<<<169, 64, 0, stream>>>(rel_tab, cpb_w1, cpb_b1, cpb_w2, table16);
  bm_build<<<(512 * 2401 + 255) / 256, 256, 0, stream>>>(table16, rel_idx, mask, bmT);
  // QKV GEMM: [100352,256] @ [768,256]^T -> bf16 qkv
  gemm_bt<false, true><<<dim3(12, 1568), 256, 0, stream>>>(x, wq, qkvb, qkvws, 768, 256);
  // attention
  attn_win<<<dim3(8, 2048), 64, 0, stream>>>(qkvws, logit_scale, bmT, aows);
  // proj GEMM: [100352,256] @ [256,256]^T -> fp32 out
  gemm_bt<true, false><<<dim3(4, 1568), 256, 0, stream>>>(aows, wp, proj_b, out, 256, 256);
}

// Round 2
// 430.125 us; speedup vs baseline: 1.3756x; 1.3756x over previous
//
#include <hip/hip_runtime.h>

#define DEV __device__ __forceinline__

typedef float  f32x4  __attribute__((ext_vector_type(4)));
typedef __bf16 bf16x8 __attribute__((ext_vector_type(8)));

DEV unsigned short f2bf(float f) {
  unsigned u = __float_as_uint(f);
  u += 0x7fffu + ((u >> 16) & 1u);           // round-to-nearest-even
  return (unsigned short)(u >> 16);
}
DEV float bf2f(unsigned short v) { return __uint_as_float(((unsigned)v) << 16); }

DEV void cp16(const void* g, void* l) {      // async global->LDS, 16B/lane
  __builtin_amdgcn_global_load_lds((const __attribute__((address_space(1))) void*)g,
                                   (__attribute__((address_space(3))) void*)l, 16, 0, 0);
}

// ---------------- prep: weights fp32->bf16 + qkv bias assembly --------------
__global__ __launch_bounds__(256) void prep_kernel(
    const float* __restrict__ qkv_w, const float* __restrict__ proj_w,
    const float* __restrict__ q_bias, const float* __restrict__ v_bias,
    unsigned short* __restrict__ wq, unsigned short* __restrict__ wp,
    float* __restrict__ qkvb)
{
  int gid = blockIdx.x * 256 + threadIdx.x;     // 1024 blocks -> 262144 = 196608+65536
  if (gid < 196608) wq[gid] = f2bf(qkv_w[gid]);
  else              wp[gid - 196608] = f2bf(proj_w[gid - 196608]);
  if (gid < 768)
    qkvb[gid] = (gid < 256) ? q_bias[gid] : ((gid < 512) ? 0.f : v_bias[gid - 512]);
}

// ---------------- x fp32 -> bf16 --------------------------------------------
__global__ __launch_bounds__(256) void xcvt(const float* __restrict__ x,
                                            unsigned short* __restrict__ xb)
{
  const size_t g = ((size_t)blockIdx.x * 256 + threadIdx.x) * 8;
  float4 a = *(const float4*)(x + g);
  float4 b = *(const float4*)(x + g + 4);
  uint4 u;
  u.x = f2bf(a.x) | ((unsigned)f2bf(a.y) << 16);
  u.y = f2bf(a.z) | ((unsigned)f2bf(a.w) << 16);
  u.z = f2bf(b.x) | ((unsigned)f2bf(b.y) << 16);
  u.w = f2bf(b.z) | ((unsigned)f2bf(b.w) << 16);
  *(uint4*)(xb + g) = u;
}

// ---------------- CPB MLP: table16[r][h] = 16*sigmoid(mlp(tab[r])) ----------
__global__ __launch_bounds__(64) void cpb_mlp(
    const float* __restrict__ tab, const float* __restrict__ w1,
    const float* __restrict__ b1, const float* __restrict__ w2,
    float* __restrict__ table16)
{
  int r = blockIdx.x;            // 169 rows
  int t = threadIdx.x;           // 64 lanes
  float x0 = tab[r * 2 + 0], x1 = tab[r * 2 + 1];
  float part[8];
#pragma unroll
  for (int h = 0; h < 8; ++h) part[h] = 0.f;
  for (int j = t; j < 512; j += 64) {
    float hv = fmaxf(w1[j * 2 + 0] * x0 + w1[j * 2 + 1] * x1 + b1[j], 0.f);
#pragma unroll
    for (int h = 0; h < 8; ++h) part[h] += hv * w2[h * 512 + j];
  }
#pragma unroll
  for (int h = 0; h < 8; ++h) {
    float v = part[h];
    for (int off = 32; off > 0; off >>= 1) v += __shfl_down(v, off, 64);
    if (t == 0) table16[r * 8 + h] = 16.f / (1.f + expf(-v));
  }
}

// -------- bias64[h][i][j] (8x64x64) and mask64[w][i][j] (64x64x64), 0-padded
__global__ __launch_bounds__(256) void bmb(
    const float* __restrict__ t16, const int* __restrict__ ridx,
    const float* __restrict__ mask, float* __restrict__ bias64,
    float* __restrict__ mask64)
{
  int gid = blockIdx.x * 256 + threadIdx.x;   // 1152 blocks = 294912 = 32768 + 262144
  int p = gid & 4095, i = p >> 6, j = p & 63;
  bool valid = (i < 49) && (j < 49);
  if (gid < 32768) {
    int h = gid >> 12;
    bias64[gid] = valid ? t16[ridx[i * 49 + j] * 8 + h] : 0.f;
  } else {
    int g2 = gid - 32768;
    int w = g2 >> 12;
    mask64[g2] = valid ? mask[w * 2401 + i * 49 + j] : 0.f;
  }
}

// ---------------- bf16 MFMA GEMM (m97-style): Y = A[M,K] @ W[N,K]^T + bias --
// 128x128 tile, BK=64, 256 thr = 4 waves (2x2 of 64x64), global_load_lds,
// XOR-swizzled LDS (16B chunk c stored at c^(row&7)) -> even bank spread.
template <bool OBF16>
__global__ __launch_bounds__(256) void gemm128(
    const unsigned short* __restrict__ A, const unsigned short* __restrict__ W,
    const float* __restrict__ bias, void* __restrict__ Yp, int N, int K)
{
  __shared__ __align__(1024) unsigned short sA[128 * 64];
  __shared__ __align__(1024) unsigned short sB[128 * 64];
  const int t = threadIdx.x, w = t >> 6, l = t & 63, quad = l >> 4, l15 = l & 15;
  const int bm = blockIdx.y * 128, bn = blockIdx.x * 128;
  const int wm = (w >> 1) * 64, wn = (w & 1) * 64;
  const int srow = t >> 3, sch = t & 7;   // staging: row = i*32+srow, chunk = sch

  f32x4 acc[4][4] = {};
  const int KT = K >> 6;
  for (int kt = 0; kt < KT; ++kt) {
    const int k0 = kt << 6;
    if (kt) __syncthreads();
#pragma unroll
    for (int i = 0; i < 4; ++i) {
      const int row = i * 32 + srow;
      const int sc  = sch ^ (srow & 7);          // row&7 == srow&7
      cp16(A + (size_t)(bm + row) * K + k0 + sc * 8, sA + (i * 256 + w * 64) * 8);
      cp16(W + (size_t)(bn + row) * K + k0 + sc * 8, sB + (i * 256 + w * 64) * 8);
    }
    __syncthreads();
#pragma unroll
    for (int kk = 0; kk < 2; ++kk) {
      bf16x8 af[4], bfr[4];
#pragma unroll
      for (int mt = 0; mt < 4; ++mt)
        af[mt] = *(const bf16x8*)&sA[(wm + mt * 16 + l15) * 64 + (((4 * kk + quad) ^ (l15 & 7)) * 8)];
#pragma unroll
      for (int nt = 0; nt < 4; ++nt)
        bfr[nt] = *(const bf16x8*)&sB[(wn + nt * 16 + l15) * 64 + (((4 * kk + quad) ^ (l15 & 7)) * 8)];
#pragma unroll
      for (int mt = 0; mt < 4; ++mt)
#pragma unroll
        for (int nt = 0; nt < 4; ++nt)
          acc[mt][nt] = __builtin_amdgcn_mfma_f32_16x16x32_bf16(af[mt], bfr[nt], acc[mt][nt], 0, 0, 0);
    }
  }
  // epilogue: D row = quad*4+r, col = l15
#pragma unroll
  for (int nt = 0; nt < 4; ++nt) {
    const int col = bn + wn + nt * 16 + l15;
    const float bv = bias[col];
#pragma unroll
    for (int mt = 0; mt < 4; ++mt) {
#pragma unroll
      for (int r = 0; r < 4; ++r) {
        const int row = bm + wm + mt * 16 + quad * 4 + r;
        float v = acc[mt][nt][r] + bv;
        if constexpr (OBF16) ((unsigned short*)Yp)[(size_t)row * N + col] = f2bf(v);
        else                 ((float*)Yp)[(size_t)row * N + col] = v;
      }
    }
  }
}

// ---------------- MFMA window attention: 1 wave per (b,h), 4 waves/block ----
// S^T = K.Q^T via mfma (frags direct from global); softmax in S^T C-layout
// (16 in-lane + quad-xor reduce); P (already /sum) -> swizzled LDS bf16;
// O^T = V^T.P^T via mfma; packed dwordx2 stores.
__global__ __launch_bounds__(256) void attn_mfma(
    const unsigned short* __restrict__ qkv, const float* __restrict__ logit_scale,
    const float* __restrict__ bias64, const float* __restrict__ mask64,
    unsigned short* __restrict__ aout)
{
  __shared__ __align__(1024) char smem[4 * 12800];
  const int w = threadIdx.x >> 6, l = threadIdx.x & 63, quad = l >> 4, l15 = l & 15;
  const int flat = blockIdx.x * 4 + w;
  const int b = flat >> 3, h = flat & 7;
  char* my = smem + w * 12800;
  unsigned short* vT = (unsigned short*)my;            // [32][64] bf16, swizzled, 4 KB
  unsigned short* P  = (unsigned short*)(my + 4096);   // [64][64] bf16, swizzled, 8 KB
  float* rq = (float*)(my + 12288);                    // 64 f32
  float* rk = (float*)(my + 12544);                    // 64 f32

  const size_t base = (size_t)b * 49 * 768 + h * 32;

  // ---- stage: per-token norms + V^T (zero-padded cols 49..63)
  if (l < 49) {
    const unsigned short* qp = qkv + base + (size_t)l * 768;
    unsigned short qb_[32], kb_[32], vb_[32];
#pragma unroll
    for (int c = 0; c < 4; ++c) {
      *(uint4*)&qb_[c * 8] = *(const uint4*)(qp + c * 8);
      *(uint4*)&kb_[c * 8] = *(const uint4*)(qp + 256 + c * 8);
      *(uint4*)&vb_[c * 8] = *(const uint4*)(qp + 512 + c * 8);
    }
    float sq = 0.f, sk = 0.f;
#pragma unroll
    for (int d = 0; d < 32; ++d) {
      float qf = bf2f(qb_[d]), kf = bf2f(kb_[d]);
      sq += qf * qf; sk += kf * kf;
    }
    const float scale = __expf(fminf(logit_scale[h], 4.60517019f));
    rq[l] = scale / fmaxf(sqrtf(sq), 1e-12f);
    rk[l] = 1.f / fmaxf(sqrtf(sk), 1e-12f);
#pragma unroll
    for (int d = 0; d < 32; ++d)
      vT[d * 64 + (((l >> 3) ^ (d & 7)) << 3) + (l & 7)] = vb_[d];
  } else {
    rq[l] = 0.f; rk[l] = 0.f;
#pragma unroll
    for (int d = 0; d < 32; ++d)
      vT[d * 64 + (((l >> 3) ^ (d & 7)) << 3) + (l & 7)] = 0;
  }
  __syncthreads();

  // ---- S^T[j][i] = sum_d K[j][d] Q[i][d]  (A-frag = K rows, B-frag = Q rows)
  f32x4 acc[4][4] = {};
  {
    const unsigned short* qb = qkv + base + quad * 8;
    const unsigned short* kb = qkv + base + 256 + quad * 8;
    bf16x8 kf[4], qf[4];
#pragma unroll
    for (int mt = 0; mt < 4; ++mt) kf[mt] = *(const bf16x8*)(kb + (size_t)(mt * 16 + l15) * 768);
#pragma unroll
    for (int nt = 0; nt < 4; ++nt) qf[nt] = *(const bf16x8*)(qb + (size_t)(nt * 16 + l15) * 768);
#pragma unroll
    for (int mt = 0; mt < 4; ++mt)
#pragma unroll
      for (int nt = 0; nt < 4; ++nt)
        acc[mt][nt] = __builtin_amdgcn_mfma_f32_16x16x32_bf16(kf[mt], qf[nt], acc[mt][nt], 0, 0, 0);
  }

  // ---- softmax per token group nt (token i = nt*16+l15), store P = p/sum
  const float* bh = bias64 + (size_t)h * 4096;
  const float* mw = mask64 + (size_t)(b & 63) * 4096;
#pragma unroll
  for (int nt = 0; nt < 4; ++nt) {
    const int i = nt * 16 + l15;
    const float rqv = rq[i];
    float s[4][4];
    float mx = -1e30f;
#pragma unroll
    for (int mt = 0; mt < 4; ++mt) {
      const int jb = mt * 16 + quad * 4;
      const f32x4 b4  = *(const f32x4*)(bh + i * 64 + jb);
      const f32x4 m4  = *(const f32x4*)(mw + i * 64 + jb);
      const f32x4 rk4 = *(const f32x4*)(rk + jb);
#pragma unroll
      for (int r = 0; r < 4; ++r) {
        float sv = acc[mt][nt][r] * (rqv * rk4[r]) + b4[r] + m4[r];
        sv = (jb + r < 49) ? sv : -1e30f;
        s[mt][r] = sv;
        mx = fmaxf(mx, sv);
      }
    }
    mx = fmaxf(mx, __shfl_xor(mx, 16, 64));
    mx = fmaxf(mx, __shfl_xor(mx, 32, 64));
    float sum = 0.f;
    float p[4][4];
#pragma unroll
    for (int mt = 0; mt < 4; ++mt)
#pragma unroll
      for (int r = 0; r < 4; ++r) {
        float pv = __expf(s[mt][r] - mx);   // masked j -> exp(-huge) = 0
        p[mt][r] = pv; sum += pv;
      }
    sum += __shfl_xor(sum, 16, 64);
    sum += __shfl_xor(sum, 32, 64);
    const float rs = 1.f / sum;
#pragma unroll
    for (int mt = 0; mt < 4; ++mt) {
      unsigned d0 = f2bf(p[mt][0] * rs) | ((unsigned)f2bf(p[mt][1] * rs) << 16);
      unsigned d1 = f2bf(p[mt][2] * rs) | ((unsigned)f2bf(p[mt][3] * rs) << 16);
      const int c = 2 * mt + (quad >> 1);            // 16B chunk of j-range
      uint2 uv; uv.x = d0; uv.y = d1;
      *(uint2*)((char*)P + i * 128 + ((c ^ (i & 7)) * 16) + (quad & 1) * 8) = uv;
    }
  }
  __syncthreads();

  // ---- O^T[d][i] = sum_j V^T[d][j] P[i][j]
  f32x4 oacc[2][4] = {};
#pragma unroll
  for (int kk = 0; kk < 2; ++kk) {
    bf16x8 vf[2], pf[4];
#pragma unroll
    for (int mt = 0; mt < 2; ++mt)
      vf[mt] = *(const bf16x8*)((char*)vT + (mt * 16 + l15) * 128 + (((4 * kk + quad) ^ (l15 & 7)) * 16));
#pragma unroll
    for (int nt = 0; nt < 4; ++nt)
      pf[nt] = *(const bf16x8*)((char*)P + (nt * 16 + l15) * 128 + (((4 * kk + quad) ^ (l15 & 7)) * 16));
#pragma unroll
    for (int mt = 0; mt < 2; ++mt)
#pragma unroll
      for (int nt = 0; nt < 4; ++nt)
        oacc[mt][nt] = __builtin_amdgcn_mfma_f32_16x16x32_bf16(vf[mt], pf[nt], oacc[mt][nt], 0, 0, 0);
  }

  // ---- store: O^T C-layout: col=token=l15(+16nt), row=d=quad*4+r(+16mt)
#pragma unroll
  for (int nt = 0; nt < 4; ++nt) {
    const int tok = nt * 16 + l15;
    if (tok < 49) {
      unsigned short* op = aout + (size_t)(b * 49 + tok) * 256 + h * 32;
#pragma unroll
      for (int mt = 0; mt < 2; ++mt) {
        unsigned u0 = f2bf(oacc[mt][nt][0]) | ((unsigned)f2bf(oacc[mt][nt][1]) << 16);
        unsigned u1 = f2bf(oacc[mt][nt][2]) | ((unsigned)f2bf(oacc[mt][nt][3]) << 16);
        uint2 uv; uv.x = u0; uv.y = u1;
        *(uint2*)(op + mt * 16 + quad * 4) = uv;
      }
    }
  }
}

// ---------------------------------------------------------------------------
extern "C" void kernel_launch(void* const* d_in, const int* in_sizes, int n_in,
                              void* d_out, int out_size, void* d_ws, size_t ws_size,
                              hipStream_t stream) {
  const float* x           = (const float*)d_in[0];
  const float* mask        = (const float*)d_in[1];
  const float* qkv_w       = (const float*)d_in[2];
  const float* q_bias      = (const float*)d_in[3];
  const float* v_bias      = (const float*)d_in[4];
  const float* logit_scale = (const float*)d_in[5];
  const float* cpb_w1      = (const float*)d_in[6];
  const float* cpb_b1      = (const float*)d_in[7];
  const float* cpb_w2      = (const float*)d_in[8];
  const float* proj_w      = (const float*)d_in[9];
  const float* proj_b      = (const float*)d_in[10];
  const float* rel_tab     = (const float*)d_in[11];
  const int*   rel_idx     = (const int*)d_in[12];
  float*       out         = (float*)d_out;

  char* ws = (char*)d_ws;
  unsigned short* qkvws   = (unsigned short*)(ws + 0);          // 100352*768*2 = 154140672
  unsigned short* shrd    = (unsigned short*)(ws + 154140672);  // 51380224: xb, then aows (overlay)
  unsigned short* wq      = (unsigned short*)(ws + 205520896);  // 393216
  unsigned short* wp      = (unsigned short*)(ws + 205914112);  // 131072
  float*          qkvb    = (float*)(ws + 206045184);           // 3072
  float*          table16 = (float*)(ws + 206048256);           // 5632 (padded)
  float*          bias64  = (float*)(ws + 206053888);           // 8*4096*4   = 131072
  float*          mask64  = (float*)(ws + 206184960);           // 64*4096*4  = 1048576
  // end: 207233536 bytes (< proven 211 MB footprint)

  prep_kernel<<<1024, 256, 0, stream>>>(qkv_w, proj_w, q_bias, v_bias, wq, wp, qkvb);
  cpb_mlp<<<169, 64, 0, stream>>>(rel_tab, cpb_w1, cpb_b1, cpb_w2, table16);
  xcvt<<<12544, 256, 0, stream>>>(x, shrd);                     // x -> bf16 (xb)
  // QKV GEMM: [100352,256]bf16 @ [768,256]^T -> bf16 qkv
  gemm128<true><<<dim3(6, 784), 256, 0, stream>>>(shrd, wq, qkvb, qkvws, 768, 256);
  bmb<<<1152, 256, 0, stream>>>(table16, rel_idx, mask, bias64, mask64);
  // attention writes aows into the xb region (xb dead after gemm1)
  attn_mfma<<<4096, 256, 0, stream>>>(qkvws, logit_scale, bias64, mask64, shrd);
  // proj GEMM: [100352,256]bf16 @ [256,256]^T -> fp32 out
  gemm128<false><<<dim3(2, 784), 256, 0, stream>>>(shrd, wp, proj_b, out, 256, 256);
}